// Round 1
// baseline (78.961 us; speedup 1.0000x reference)
//
#include <hip/hip_runtime.h>

#define NB 8
#define NH 128
#define NW 128
#define NC 64
#define NF 64

// wsum[di][c][fch] = (sum_dj conv_w[di][dj][c][fch]) * scale[fch]; bias[fch] appended.
__global__ __launch_bounds__(256) void prep_kernel(
    const float* __restrict__ conv_w, const float* __restrict__ gamma,
    const float* __restrict__ beta, const float* __restrict__ mean,
    const float* __restrict__ var, float* __restrict__ ws) {
  int idx = blockIdx.x * 256 + threadIdx.x;
  if (idx >= 3 * 64 * 64) return;
  int di  = idx >> 12;      // / 4096
  int rem = idx & 4095;
  int c   = rem >> 6;
  int fch = rem & 63;
  float s = gamma[fch] * rsqrtf(var[fch] + 1e-3f);
  float v = conv_w[((di * 3 + 0) * 64 + c) * 64 + fch]
          + conv_w[((di * 3 + 1) * 64 + c) * 64 + fch]
          + conv_w[((di * 3 + 2) * 64 + c) * 64 + fch];
  ws[idx] = v * s;
  if (idx < 64) {
    float s2 = gamma[idx] * rsqrtf(var[idx] + 1e-3f);
    ws[3 * 64 * 64 + idx] = beta[idx] - mean[idx] * s2;
  }
}

__global__ __launch_bounds__(256) void main_kernel(
    const float* __restrict__ fmap, const float* __restrict__ y2,
    const float* __restrict__ wsum, float* __restrict__ out) {
  __shared__ int   s_idx[4][384];
  __shared__ float s_wt[4][384];
  __shared__ float fs[64][132];   // row pad to 132 floats (528B, 16B-aligned)
  __shared__ float wsm[64][64];

  const int t  = threadIdx.x;
  const int b  = blockIdx.x >> 7;
  const int oi = blockIdx.x & 127;
  const float* fmapb = fmap + (size_t)b * (128 * 128 * 64);

  // ---- Phase 0: per-sample coords/weights (u = di*128 + oj; j = u/3, a = u%3) ----
  for (int u = t; u < 384; u += 256) {
    int j = u / 3;
    int a = u - j * 3;
    const float4* yp = reinterpret_cast<const float4*>(
        y2 + ((size_t)(b * 128 + oi) * 128 + j) * 8);
    float4 xv = yp[0];
    float4 yv = yp[1];

    float hi01 = fmaxf(xv.x, xv.y), lo01 = fminf(xv.x, xv.y);
    float hi23 = fmaxf(xv.z, xv.w), lo23 = fminf(xv.z, xv.w);
    float top1 = fmaxf(hi01, hi23);
    float top2 = fmaxf(fminf(hi01, hi23), (hi01 >= hi23) ? lo01 : lo23);
    float w = fminf(fmaxf(top1, 1.f), 127.f) + fminf(fmaxf(top2, 1.f), 127.f);

    hi01 = fmaxf(yv.x, yv.y); lo01 = fminf(yv.x, yv.y);
    hi23 = fmaxf(yv.z, yv.w); lo23 = fminf(yv.z, yv.w);
    top1 = fmaxf(hi01, hi23);
    top2 = fmaxf(fminf(hi01, hi23), (hi01 >= hi23) ? lo01 : lo23);
    float h = fminf(fmaxf(top1, 1.f), 127.f) + fminf(fmaxf(top2, 1.f), 127.f);

    float x, yy;
    if (a == 0)      { x = ((float)j - 1.0f) - w / 3.0f;  yy = ((float)oi - 1.0f) - h / 3.0f; }
    else if (a == 1) { x = (float)j + w * 1e-10f;         yy = (float)oi + h * 1e-10f; }
    else             { x = ((float)j + 1.0f) + w / 3.0f;  yy = ((float)oi + 1.0f) + h / 3.0f; }

    float xl = fminf(fmaxf(floorf(x), 0.f), 127.f);
    float xr = fminf(fmaxf(ceilf(x),  0.f), 127.f);
    float yt = fminf(fmaxf(floorf(yy), 0.f), 127.f);
    float yb = fminf(fmaxf(ceilf(yy),  0.f), 127.f);
    int ixl = (int)xl, ixr = (int)xr, iyt = (int)yt, iyb = (int)yb;
    s_idx[0][u] = (iyt * 128 + ixl) * 64;  // lt
    s_idx[1][u] = (iyt * 128 + ixr) * 64;  // rt
    s_idx[2][u] = (iyb * 128 + ixl) * 64;  // lb
    s_idx[3][u] = (iyb * 128 + ixr) * 64;  // rb
    s_wt[0][u] = xr - x;   // xr_x
    s_wt[1][u] = x - xl;   // xl_x
    s_wt[2][u] = yy - yt;  // yt_y
    s_wt[3][u] = yb - yy;  // yb_y
  }

  const int fchg = t & 7;   // 8 fch per thread
  const int pxg  = t >> 3;  // 32 groups of 4 px
  float bias[8];
  {
    const float4* bp = reinterpret_cast<const float4*>(wsum + 3 * 64 * 64 + fchg * 8);
    float4 b0 = bp[0], b1 = bp[1];
    bias[0] = b0.x; bias[1] = b0.y; bias[2] = b0.z; bias[3] = b0.w;
    bias[4] = b1.x; bias[5] = b1.y; bias[6] = b1.z; bias[7] = b1.w;
  }
  float acc[4][8];
  #pragma unroll
  for (int i = 0; i < 4; ++i)
    #pragma unroll
    for (int k = 0; k < 8; ++k) acc[i][k] = 0.f;

  __syncthreads();

  for (int di = 0; di < 3; ++di) {
    // stage wsum[di] chunk to LDS
    {
      const float4* src = reinterpret_cast<const float4*>(wsum + di * 4096);
      float4* dst = reinterpret_cast<float4*>(&wsm[0][0]);
      for (int k2 = t; k2 < 1024; k2 += 256) dst[k2] = src[k2];
    }
    // sampling: fs[c][oj] = bilinear sample for u = di*128+oj, channel c
    {
      const int c  = t & 63;
      const int q0 = t >> 6;  // 0..3
      for (int q = q0; q < 32; q += 4) {
        float v0, v1, v2, v3;
        #pragma unroll
        for (int r = 0; r < 4; ++r) {
          int u = di * 128 + q * 4 + r;
          float flt = fmapb[s_idx[0][u] + c];
          float frt = fmapb[s_idx[1][u] + c];
          float flb = fmapb[s_idx[2][u] + c];
          float frb = fmapb[s_idx[3][u] + c];
          float xr_x = s_wt[0][u], xl_x = s_wt[1][u];
          float yt_y = s_wt[2][u], yb_y = s_wt[3][u];
          float val = (xr_x * flt + xl_x * flb) * yb_y
                    + (xr_x * frt + xl_x * frb) * yt_y;
          if (r == 0) v0 = val; else if (r == 1) v1 = val;
          else if (r == 2) v2 = val; else v3 = val;
        }
        *reinterpret_cast<float4*>(&fs[c][q * 4]) = make_float4(v0, v1, v2, v3);
      }
    }
    __syncthreads();
    // GEMM: acc[px][fch] += fs[c][pxg*4+px] * wsm[c][fchg*8+fch]
    #pragma unroll 4
    for (int c = 0; c < 64; ++c) {
      float4 f4 = *reinterpret_cast<const float4*>(&fs[c][pxg * 4]);
      float4 w0 = *reinterpret_cast<const float4*>(&wsm[c][fchg * 8]);
      float4 w1 = *reinterpret_cast<const float4*>(&wsm[c][fchg * 8 + 4]);
      float fv[4] = {f4.x, f4.y, f4.z, f4.w};
      float wv[8] = {w0.x, w0.y, w0.z, w0.w, w1.x, w1.y, w1.z, w1.w};
      #pragma unroll
      for (int i = 0; i < 4; ++i)
        #pragma unroll
        for (int k = 0; k < 8; ++k)
          acc[i][k] = fmaf(fv[i], wv[k], acc[i][k]);
    }
    __syncthreads();
  }

  // epilogue: BN already folded into wsum/bias; apply bias + ReLU
  {
    float* ob = out + (((size_t)(b * 128 + oi) * 128) + pxg * 4) * 64 + fchg * 8;
    #pragma unroll
    for (int i = 0; i < 4; ++i) {
      float4 o0, o1;
      o0.x = fmaxf(acc[i][0] + bias[0], 0.f);
      o0.y = fmaxf(acc[i][1] + bias[1], 0.f);
      o0.z = fmaxf(acc[i][2] + bias[2], 0.f);
      o0.w = fmaxf(acc[i][3] + bias[3], 0.f);
      o1.x = fmaxf(acc[i][4] + bias[4], 0.f);
      o1.y = fmaxf(acc[i][5] + bias[5], 0.f);
      o1.z = fmaxf(acc[i][6] + bias[6], 0.f);
      o1.w = fmaxf(acc[i][7] + bias[7], 0.f);
      *reinterpret_cast<float4*>(ob + i * 64)     = o0;
      *reinterpret_cast<float4*>(ob + i * 64 + 4) = o1;
    }
  }
}

extern "C" void kernel_launch(void* const* d_in, const int* in_sizes, int n_in,
                              void* d_out, int out_size, void* d_ws, size_t ws_size,
                              hipStream_t stream) {
  const float* fmap   = (const float*)d_in[0];
  const float* y2     = (const float*)d_in[1];
  const float* conv_w = (const float*)d_in[2];
  const float* gamma  = (const float*)d_in[3];
  const float* beta   = (const float*)d_in[4];
  const float* mean   = (const float*)d_in[5];
  const float* var    = (const float*)d_in[6];
  float* outp = (float*)d_out;
  float* ws   = (float*)d_ws;

  prep_kernel<<<48, 256, 0, stream>>>(conv_w, gamma, beta, mean, var, ws);
  main_kernel<<<NB * NH, 256, 0, stream>>>(fmap, y2, ws, outp);
}

// Round 2
// 34.103 us; speedup vs baseline: 2.3154x; 2.3154x over previous
//
#include <hip/hip_runtime.h>

typedef __bf16 bf16x8 __attribute__((ext_vector_type(8)));
typedef float f32x4 __attribute__((ext_vector_type(4)));

__device__ __forceinline__ unsigned short f2bf(float f) {
  __bf16 h = (__bf16)f;
  return __builtin_bit_cast(unsigned short, h);
}

// d_ws layout: [0, 24576) bytes: wsB bf16 fragment-ordered (12288 shorts)
//              [24576, 24832): bias (64 floats)
// wsB flat idx = (((di*4 + jblk)*2 + kstep)*64 + lane)*8 + i
//   c   = kstep*32 + 4*(lane>>4) + (i&3) + 16*(i>>2)   (k within 32-step)
//   fch = jblk*16 + (lane&15)
// Any consistent (lane,i)->k bijection is correct as long as A uses the same one.
__global__ __launch_bounds__(256) void prep_kernel(
    const float* __restrict__ conv_w, const float* __restrict__ gamma,
    const float* __restrict__ beta, const float* __restrict__ mean,
    const float* __restrict__ var, unsigned short* __restrict__ wsB,
    float* __restrict__ bias) {
  int idx = blockIdx.x * 256 + threadIdx.x;
  if (idx >= 12288) return;
  int di    = idx >> 12;
  int r     = idx & 4095;
  int jblk  = r >> 10;
  int r2    = r & 1023;
  int kstep = r2 >> 9;
  int r3    = r2 & 511;
  int lane  = r3 >> 3;
  int i     = r3 & 7;
  int c   = kstep * 32 + 4 * (lane >> 4) + (i & 3) + 16 * (i >> 2);
  int fch = jblk * 16 + (lane & 15);
  float s = gamma[fch] * rsqrtf(var[fch] + 1e-3f);
  float v = conv_w[((di * 3 + 0) * 64 + c) * 64 + fch]
          + conv_w[((di * 3 + 1) * 64 + c) * 64 + fch]
          + conv_w[((di * 3 + 2) * 64 + c) * 64 + fch];
  wsB[idx] = f2bf(v * s);
  if (idx < 64) bias[idx] = beta[idx] - mean[idx] * (gamma[idx] * rsqrtf(var[idx] + 1e-3f));
}

__global__ __launch_bounds__(256, 4) void main_kernel(
    const float* __restrict__ fmap, const float* __restrict__ y2,
    const uint4* __restrict__ wsBq, const float* __restrict__ biasg,
    float* __restrict__ out) {
  __shared__ int   s_idx[4][384];
  __shared__ float s_wt[4][384];
  __shared__ uint2 fsA[16][64][2];  // [pxblk*2+kstep][lane][half], 16KB, lane-linear

  const int t    = threadIdx.x;
  const int lane = t & 63;
  const int wave = t >> 6;
  // XCD swizzle: blockIdx%8 ~ XCD id -> pin one batch per XCD (fmap_b ~ 4.2MB ~ L2)
  const int b  = blockIdx.x & 7;
  const int oi = blockIdx.x >> 3;
  const float* fmapb = fmap + (size_t)b * (128 * 128 * 64);

  // ---- Phase 0: per-sample coords/weights (u = di*128 + oj; j = u/3, a = u%3) ----
  for (int u = t; u < 384; u += 256) {
    int j = u / 3;
    int a = u - j * 3;
    const float4* yp = reinterpret_cast<const float4*>(
        y2 + ((size_t)(b * 128 + oi) * 128 + j) * 8);
    float4 xv = yp[0];
    float4 yv = yp[1];

    float hi01 = fmaxf(xv.x, xv.y), lo01 = fminf(xv.x, xv.y);
    float hi23 = fmaxf(xv.z, xv.w), lo23 = fminf(xv.z, xv.w);
    float top1 = fmaxf(hi01, hi23);
    float top2 = fmaxf(fminf(hi01, hi23), (hi01 >= hi23) ? lo01 : lo23);
    float w = fminf(fmaxf(top1, 1.f), 127.f) + fminf(fmaxf(top2, 1.f), 127.f);

    hi01 = fmaxf(yv.x, yv.y); lo01 = fminf(yv.x, yv.y);
    hi23 = fmaxf(yv.z, yv.w); lo23 = fminf(yv.z, yv.w);
    top1 = fmaxf(hi01, hi23);
    top2 = fmaxf(fminf(hi01, hi23), (hi01 >= hi23) ? lo01 : lo23);
    float h = fminf(fmaxf(top1, 1.f), 127.f) + fminf(fmaxf(top2, 1.f), 127.f);

    float x, yy;
    if (a == 0)      { x = ((float)j - 1.0f) - w / 3.0f;  yy = ((float)oi - 1.0f) - h / 3.0f; }
    else if (a == 1) { x = (float)j + w * 1e-10f;         yy = (float)oi + h * 1e-10f; }
    else             { x = ((float)j + 1.0f) + w / 3.0f;  yy = ((float)oi + 1.0f) + h / 3.0f; }

    float xl = fminf(fmaxf(floorf(x), 0.f), 127.f);
    float xr = fminf(fmaxf(ceilf(x),  0.f), 127.f);
    float yt = fminf(fmaxf(floorf(yy), 0.f), 127.f);
    float yb = fminf(fmaxf(ceilf(yy),  0.f), 127.f);
    int ixl = (int)xl, ixr = (int)xr, iyt = (int)yt, iyb = (int)yb;
    s_idx[0][u] = (iyt * 128 + ixl) * 64;  // lt
    s_idx[1][u] = (iyt * 128 + ixr) * 64;  // rt
    s_idx[2][u] = (iyb * 128 + ixl) * 64;  // lb
    s_idx[3][u] = (iyb * 128 + ixr) * 64;  // rb
    s_wt[0][u] = xr - x;   // xr_x
    s_wt[1][u] = x - xl;   // xl_x
    s_wt[2][u] = yy - yt;  // yt_y
    s_wt[3][u] = yb - yy;  // yb_y
  }
  __syncthreads();

  float bias4[4];
  #pragma unroll
  for (int j = 0; j < 4; ++j) bias4[j] = biasg[j * 16 + (lane & 15)];

  f32x4 acc[2][4];
  #pragma unroll
  for (int p = 0; p < 2; ++p)
    #pragma unroll
    for (int j = 0; j < 4; ++j)
      acc[p][j] = (f32x4){0.f, 0.f, 0.f, 0.f};

  for (int di = 0; di < 3; ++di) {
    // B fragments for this di: per-lane 16B from L2-resident d_ws (24KB total)
    bf16x8 Bf[8];
    #pragma unroll
    for (int jk = 0; jk < 8; ++jk)
      Bf[jk] = __builtin_bit_cast(bf16x8, wsBq[(di * 8 + jk) * 64 + lane]);

    // ---- Sampling: 2048 tasks = 128 px * 16 channel-quads ----
    #pragma unroll 2
    for (int r = 0; r < 8; ++r) {
      int task = t + 256 * r;
      int up = task >> 4;      // output pixel oj
      int cg = task & 15;      // channel quad
      int c0 = cg * 4;
      int u  = di * 128 + up;
      int i0 = s_idx[0][u], i1 = s_idx[1][u], i2 = s_idx[2][u], i3 = s_idx[3][u];
      float4 lt = *reinterpret_cast<const float4*>(fmapb + i0 + c0);
      float4 rt = *reinterpret_cast<const float4*>(fmapb + i1 + c0);
      float4 lb = *reinterpret_cast<const float4*>(fmapb + i2 + c0);
      float4 rb = *reinterpret_cast<const float4*>(fmapb + i3 + c0);
      float xr_x = s_wt[0][u], xl_x = s_wt[1][u];
      float yt_y = s_wt[2][u], yb_y = s_wt[3][u];
      float v0 = (xr_x * lt.x + xl_x * lb.x) * yb_y + (xr_x * rt.x + xl_x * rb.x) * yt_y;
      float v1 = (xr_x * lt.y + xl_x * lb.y) * yb_y + (xr_x * rt.y + xl_x * rb.y) * yt_y;
      float v2 = (xr_x * lt.z + xl_x * lb.z) * yb_y + (xr_x * rt.z + xl_x * rb.z) * yt_y;
      float v3 = (xr_x * lt.w + xl_x * lb.w) * yb_y + (xr_x * rt.w + xl_x * rb.w) * yt_y;
      uint2 q;
      q.x = (unsigned)f2bf(v0) | ((unsigned)f2bf(v1) << 16);
      q.y = (unsigned)f2bf(v2) | ((unsigned)f2bf(v3) << 16);
      // frag dest: k = 4*g + (i&3) + 16*h  (same bijection as prep)
      int kstep = cg >> 3, g = cg & 3, h = (cg >> 2) & 1;
      fsA[(up >> 4) * 2 + kstep][(up & 15) + 16 * g][h] = q;
    }
    __syncthreads();

    // ---- MFMA GEMM: wave owns pxblks {2w, 2w+1}, all 4 fch blocks ----
    #pragma unroll
    for (int kstep = 0; kstep < 2; ++kstep) {
      #pragma unroll
      for (int p = 0; p < 2; ++p) {
        int pxblk = wave * 2 + p;
        bf16x8 a = __builtin_bit_cast(bf16x8,
            *reinterpret_cast<const uint4*>(&fsA[pxblk * 2 + kstep][lane][0]));
        #pragma unroll
        for (int j = 0; j < 4; ++j)
          acc[p][j] = __builtin_amdgcn_mfma_f32_16x16x32_bf16(a, Bf[j * 2 + kstep],
                                                              acc[p][j], 0, 0, 0);
      }
    }
    __syncthreads();
  }

  // ---- Epilogue: bias + ReLU; C/D layout col=lane&15, row=(lane>>4)*4+reg ----
  float* outb = out + ((size_t)(b * 128 + oi) * 128) * 64;
  #pragma unroll
  for (int p = 0; p < 2; ++p) {
    int pxB = (wave * 2 + p) * 16 + (lane >> 4) * 4;
    #pragma unroll
    for (int j = 0; j < 4; ++j) {
      int fch = j * 16 + (lane & 15);
      #pragma unroll
      for (int reg = 0; reg < 4; ++reg) {
        float v = acc[p][j][reg] + bias4[j];
        outb[(size_t)(pxB + reg) * 64 + fch] = fmaxf(v, 0.f);
      }
    }
  }
}

extern "C" void kernel_launch(void* const* d_in, const int* in_sizes, int n_in,
                              void* d_out, int out_size, void* d_ws, size_t ws_size,
                              hipStream_t stream) {
  const float* fmap   = (const float*)d_in[0];
  const float* y2     = (const float*)d_in[1];
  const float* conv_w = (const float*)d_in[2];
  const float* gamma  = (const float*)d_in[3];
  const float* beta   = (const float*)d_in[4];
  const float* mean   = (const float*)d_in[5];
  const float* var    = (const float*)d_in[6];
  float* outp = (float*)d_out;

  unsigned short* wsB = (unsigned short*)d_ws;
  float* bias = (float*)((char*)d_ws + 24576);

  prep_kernel<<<48, 256, 0, stream>>>(conv_w, gamma, beta, mean, var, wsB, bias);
  main_kernel<<<1024, 256, 0, stream>>>(fmap, y2, (const uint4*)d_ws, bias, outp);
}

// Round 3
// 30.859 us; speedup vs baseline: 2.5588x; 1.1051x over previous
//
#include <hip/hip_runtime.h>

typedef __bf16 bf16x8 __attribute__((ext_vector_type(8)));
typedef float f32x4 __attribute__((ext_vector_type(4)));

__device__ __forceinline__ unsigned short f2bf(float f) {
  __bf16 h = (__bf16)f;
  return __builtin_bit_cast(unsigned short, h);
}

// d_ws layout: [0, 24576) bytes: wsB bf16 fragment-ordered (12288 shorts)
//              [24576, 24832): bias (64 floats)
// wsB flat idx = (((di*4 + jblk)*2 + kstep)*64 + lane)*8 + i
//   c   = kstep*32 + 4*(lane>>4) + (i&3) + 16*(i>>2)
//   fch = jblk*16 + (lane&15)
__global__ __launch_bounds__(256) void prep_kernel(
    const float* __restrict__ conv_w, const float* __restrict__ gamma,
    const float* __restrict__ beta, const float* __restrict__ mean,
    const float* __restrict__ var, unsigned short* __restrict__ wsB,
    float* __restrict__ bias) {
  int idx = blockIdx.x * 256 + threadIdx.x;
  if (idx >= 12288) return;
  int di    = idx >> 12;
  int r     = idx & 4095;
  int jblk  = r >> 10;
  int r2    = r & 1023;
  int kstep = r2 >> 9;
  int r3    = r2 & 511;
  int lane  = r3 >> 3;
  int i     = r3 & 7;
  int c   = kstep * 32 + 4 * (lane >> 4) + (i & 3) + 16 * (i >> 2);
  int fch = jblk * 16 + (lane & 15);
  float s = gamma[fch] * rsqrtf(var[fch] + 1e-3f);
  float v = conv_w[((di * 3 + 0) * 64 + c) * 64 + fch]
          + conv_w[((di * 3 + 1) * 64 + c) * 64 + fch]
          + conv_w[((di * 3 + 2) * 64 + c) * 64 + fch];
  wsB[idx] = f2bf(v * s);
  if (idx < 64) bias[idx] = beta[idx] - mean[idx] * (gamma[idx] * rsqrtf(var[idx] + 1e-3f));
}

__global__ __launch_bounds__(256, 4) void main_kernel(
    const float* __restrict__ fmap, const float* __restrict__ y2,
    const uint4* __restrict__ wsBq, const float* __restrict__ biasg,
    float* __restrict__ out) {
  __shared__ int   s_idx[4][384];
  __shared__ float s_wt[4][384];
  __shared__ uint2 fsA[16][64][2];      // swizzled slot: l' = l ^ 2*(l>>4)
  __shared__ unsigned char lst[3][128]; // per-di compacted px list: nz first
  __shared__ int cnt[3], zc[3];

  const int t    = threadIdx.x;
  const int lane = t & 63;
  const int wave = t >> 6;
  // XCD swizzle: pin one batch (4.2MB fmap ~ one XCD L2) per XCD
  const int b  = blockIdx.x & 7;
  const int oi = blockIdx.x >> 3;
  const float* fmapb = fmap + (size_t)b * (128 * 128 * 64);

  if (t < 3) cnt[t] = 0;
  else if (t < 6) zc[t - 3] = 0;
  __syncthreads();

  // ---- Phase 0: per-sample coords/weights (u = di*128 + up; j = u/3, a = u%3) ----
  for (int u = t; u < 384; u += 256) {
    int j = u / 3;
    int a = u - j * 3;
    const float4* yp = reinterpret_cast<const float4*>(
        y2 + ((size_t)(b * 128 + oi) * 128 + j) * 8);
    float4 xv = yp[0];
    float4 yv = yp[1];

    float hi01 = fmaxf(xv.x, xv.y), lo01 = fminf(xv.x, xv.y);
    float hi23 = fmaxf(xv.z, xv.w), lo23 = fminf(xv.z, xv.w);
    float top1 = fmaxf(hi01, hi23);
    float top2 = fmaxf(fminf(hi01, hi23), (hi01 >= hi23) ? lo01 : lo23);
    float w = fminf(fmaxf(top1, 1.f), 127.f) + fminf(fmaxf(top2, 1.f), 127.f);

    hi01 = fmaxf(yv.x, yv.y); lo01 = fminf(yv.x, yv.y);
    hi23 = fmaxf(yv.z, yv.w); lo23 = fminf(yv.z, yv.w);
    top1 = fmaxf(hi01, hi23);
    top2 = fmaxf(fminf(hi01, hi23), (hi01 >= hi23) ? lo01 : lo23);
    float h = fminf(fmaxf(top1, 1.f), 127.f) + fminf(fmaxf(top2, 1.f), 127.f);

    float x, yy;
    if (a == 0)      { x = ((float)j - 1.0f) - w / 3.0f;  yy = ((float)oi - 1.0f) - h / 3.0f; }
    else if (a == 1) { x = (float)j + w * 1e-10f;         yy = (float)oi + h * 1e-10f; }
    else             { x = ((float)j + 1.0f) + w / 3.0f;  yy = ((float)oi + 1.0f) + h / 3.0f; }

    float xl = fminf(fmaxf(floorf(x), 0.f), 127.f);
    float xr = fminf(fmaxf(ceilf(x),  0.f), 127.f);
    float yt = fminf(fmaxf(floorf(yy), 0.f), 127.f);
    float yb = fminf(fmaxf(ceilf(yy),  0.f), 127.f);
    int ixl = (int)xl, ixr = (int)xr, iyt = (int)yt, iyb = (int)yb;
    s_idx[0][u] = (iyt * 128 + ixl) * 64;  // lt
    s_idx[1][u] = (iyt * 128 + ixr) * 64;  // rt
    s_idx[2][u] = (iyb * 128 + ixl) * 64;  // lb
    s_idx[3][u] = (iyb * 128 + ixr) * 64;  // rb
    float xr_x = xr - x, xl_x = x - xl, yt_y = yy - yt, yb_y = yb - yy;
    s_wt[0][u] = xr_x;
    s_wt[1][u] = xl_x;
    s_wt[2][u] = yt_y;
    s_wt[3][u] = yb_y;

    // compaction: sample is identically zero if x-weights or y-weights both 0
    bool need = ((xr_x != 0.f) || (xl_x != 0.f)) && ((yb_y != 0.f) || (yt_y != 0.f));
    int di = u >> 7;
    int up = u & 127;
    int pos = need ? atomicAdd(&cnt[di], 1) : (127 - atomicAdd(&zc[di], 1));
    lst[di][pos] = (unsigned char)up;
  }
  __syncthreads();

  float bias4[4];
  #pragma unroll
  for (int j = 0; j < 4; ++j) bias4[j] = biasg[j * 16 + (lane & 15)];

  f32x4 acc[2][4];
  #pragma unroll
  for (int p = 0; p < 2; ++p)
    #pragma unroll
    for (int j = 0; j < 4; ++j)
      acc[p][j] = (f32x4){bias4[j], bias4[j], bias4[j], bias4[j]};

  for (int di = 0; di < 3; ++di) {
    // B fragments for this di (L2-resident, 24KB total)
    bf16x8 Bf[8];
    #pragma unroll
    for (int jk = 0; jk < 8; ++jk)
      Bf[jk] = __builtin_bit_cast(bf16x8, wsBq[(di * 8 + jk) * 64 + lane]);

    const int nzc = cnt[di];

    // ---- Sampling: 2048 tasks = 128 px-list entries * 16 channel-quads ----
    #pragma unroll 2
    for (int r = 0; r < 8; ++r) {
      int task = t + 256 * r;
      int gidx = task >> 4;      // list position
      int cg   = task & 15;      // channel quad
      int up   = lst[di][gidx];
      int kstep = cg >> 3, g = cg & 3, hh = (cg >> 2) & 1;
      int sA  = (up >> 4) * 2 + kstep;
      int lA  = (up & 15) + 16 * g;
      int lsw = lA ^ (2 * g);    // bank swizzle
      uint2 q = make_uint2(0u, 0u);
      if (gidx < nzc) {
        int c0 = cg * 4;
        int u  = di * 128 + up;
        int i0 = s_idx[0][u], i1 = s_idx[1][u], i2 = s_idx[2][u], i3 = s_idx[3][u];
        float4 lt = *reinterpret_cast<const float4*>(fmapb + i0 + c0);
        float4 rt = *reinterpret_cast<const float4*>(fmapb + i1 + c0);
        float4 lb = *reinterpret_cast<const float4*>(fmapb + i2 + c0);
        float4 rb = *reinterpret_cast<const float4*>(fmapb + i3 + c0);
        float xr_x = s_wt[0][u], xl_x = s_wt[1][u];
        float yt_y = s_wt[2][u], yb_y = s_wt[3][u];
        float v0 = (xr_x * lt.x + xl_x * lb.x) * yb_y + (xr_x * rt.x + xl_x * rb.x) * yt_y;
        float v1 = (xr_x * lt.y + xl_x * lb.y) * yb_y + (xr_x * rt.y + xl_x * rb.y) * yt_y;
        float v2 = (xr_x * lt.z + xl_x * lb.z) * yb_y + (xr_x * rt.z + xl_x * rb.z) * yt_y;
        float v3 = (xr_x * lt.w + xl_x * lb.w) * yb_y + (xr_x * rt.w + xl_x * rb.w) * yt_y;
        q.x = (unsigned)f2bf(v0) | ((unsigned)f2bf(v1) << 16);
        q.y = (unsigned)f2bf(v2) | ((unsigned)f2bf(v3) << 16);
      }
      fsA[sA][lsw][hh] = q;
    }
    __syncthreads();

    // ---- MFMA GEMM: wave owns pxblks {2w, 2w+1}, all 4 fch blocks ----
    const int lsr = lane ^ (2 * (lane >> 4));  // read-side swizzle
    #pragma unroll
    for (int kstep = 0; kstep < 2; ++kstep) {
      #pragma unroll
      for (int p = 0; p < 2; ++p) {
        int pxblk = wave * 2 + p;
        bf16x8 a = __builtin_bit_cast(bf16x8,
            *reinterpret_cast<const uint4*>(&fsA[pxblk * 2 + kstep][lsr][0]));
        #pragma unroll
        for (int j = 0; j < 4; ++j)
          acc[p][j] = __builtin_amdgcn_mfma_f32_16x16x32_bf16(a, Bf[j * 2 + kstep],
                                                              acc[p][j], 0, 0, 0);
      }
    }
    __syncthreads();
  }

  // ---- Epilogue: ReLU (bias pre-folded); C/D: col=lane&15, row=(lane>>4)*4+reg ----
  float* outb = out + ((size_t)(b * 128 + oi) * 128) * 64;
  #pragma unroll
  for (int p = 0; p < 2; ++p) {
    int pxB = (wave * 2 + p) * 16 + (lane >> 4) * 4;
    #pragma unroll
    for (int j = 0; j < 4; ++j) {
      int fch = j * 16 + (lane & 15);
      #pragma unroll
      for (int reg = 0; reg < 4; ++reg) {
        outb[(size_t)(pxB + reg) * 64 + fch] = fmaxf(acc[p][j][reg], 0.f);
      }
    }
  }
}

extern "C" void kernel_launch(void* const* d_in, const int* in_sizes, int n_in,
                              void* d_out, int out_size, void* d_ws, size_t ws_size,
                              hipStream_t stream) {
  const float* fmap   = (const float*)d_in[0];
  const float* y2     = (const float*)d_in[1];
  const float* conv_w = (const float*)d_in[2];
  const float* gamma  = (const float*)d_in[3];
  const float* beta   = (const float*)d_in[4];
  const float* mean   = (const float*)d_in[5];
  const float* var    = (const float*)d_in[6];
  float* outp = (float*)d_out;

  unsigned short* wsB = (unsigned short*)d_ws;
  float* bias = (float*)((char*)d_ws + 24576);

  prep_kernel<<<48, 256, 0, stream>>>(conv_w, gamma, beta, mean, var, wsB, bias);
  main_kernel<<<1024, 256, 0, stream>>>(fmap, y2, (const uint4*)d_ws, bias, outp);
}